// Round 7
// baseline (1376.842 us; speedup 1.0000x reference)
//
#include <hip/hip_runtime.h>

#define NN 100000
#define NE 3200000
#define HID 64
#define NPB 128                         // nodes per bucket (dstlocal = dst & 127)
#define NB  ((NN + NPB - 1) / NPB)      // 782 buckets
#define CHUNK 4096                      // edges per hist/scatter workgroup
#define NCH ((NE + CHUNK - 1) / CHUNK)  // 782 chunks
#define CAP 5632                        // per-bucket record capacity (mean 4092, sd 64)

// ws layout (4B words), ~28 MB:
//  [0, 2*NE)    rec (int2: .x = src | dstlocal<<20, .y = ew bits) — sorted in place
//  then sx[2NN] (float2: s1,x), p[NN], r[NN], nbase[NN], nend[NN], ghist[NB], gbase[NB], gcur[NB]

// -------- global histogram over dst buckets --------
__global__ __launch_bounds__(256) void k_hist(const int* __restrict__ dst,
                                              int* __restrict__ ghist) {
    __shared__ int sh[NB];
    for (int j = threadIdx.x; j < NB; j += 256) sh[j] = 0;
    __syncthreads();
    const long long b0 = (long long)blockIdx.x * CHUNK;
    #pragma unroll
    for (int k = 0; k < CHUNK / 256; ++k) {
        long long e = b0 + k * 256 + threadIdx.x;
        if (e < NE) atomicAdd(&sh[dst[e] >> 7], 1);
    }
    __syncthreads();
    for (int j = threadIdx.x; j < NB; j += 256) {
        int c = sh[j];
        if (c) atomicAdd(&ghist[j], c);
    }
}

// -------- exclusive scan of NB bucket counts (single WG) --------
__global__ void k_scan(const int* __restrict__ ghist, int* __restrict__ gbase,
                       int* __restrict__ gcur) {
    __shared__ int sh[1024];
    const int tid = threadIdx.x;
    int v = (tid < NB) ? ghist[tid] : 0;
    sh[tid] = v;
    __syncthreads();
    #pragma unroll
    for (int off = 1; off < 1024; off <<= 1) {
        int t = (tid >= off) ? sh[tid - off] : 0;
        __syncthreads();
        sh[tid] += t;
        __syncthreads();
    }
    if (tid < NB) {
        int b = sh[tid] - v;
        gbase[tid] = b;
        gcur[tid] = b;
    }
}

// -------- bucketed scatter: LDS-staged, one reservation atomic per (WG,bucket) --------
__global__ __launch_bounds__(256) void k_scatter(const int* __restrict__ src,
                                                 const int* __restrict__ dst,
                                                 const float* __restrict__ ew,
                                                 int* __restrict__ gcur,
                                                 int2* __restrict__ rec) {
    __shared__ int sh_px[CHUNK];
    __shared__ int sh_w[CHUNK];
    __shared__ unsigned short sh_b[CHUNK];
    __shared__ int sh_cnt[NB];
    __shared__ int sh_base[NB];
    for (int j = threadIdx.x; j < NB; j += 256) sh_cnt[j] = 0;
    __syncthreads();
    const long long b0 = (long long)blockIdx.x * CHUNK;
    #pragma unroll
    for (int k = 0; k < CHUNK / 256; ++k) {
        int idx = k * 256 + threadIdx.x;
        long long e = b0 + idx;
        if (e < NE) {
            int d = dst[e];
            int b = d >> 7;
            sh_px[idx] = src[e] | ((d & 127) << 20);   // src < 2^20
            sh_w[idx] = __float_as_int(ew[e]);
            sh_b[idx] = (unsigned short)b;
            atomicAdd(&sh_cnt[b], 1);
        }
    }
    __syncthreads();
    for (int j = threadIdx.x; j < NB; j += 256) {
        int c = sh_cnt[j];
        sh_base[j] = c ? atomicAdd(&gcur[j], c) : 0;
        sh_cnt[j] = 0;                                  // reuse as running offset
    }
    __syncthreads();
    #pragma unroll
    for (int k = 0; k < CHUNK / 256; ++k) {
        int idx = k * 256 + threadIdx.x;
        long long e = b0 + idx;
        if (e < NE) {
            int b = sh_b[idx];
            int off = atomicAdd(&sh_cnt[b], 1);
            rec[sh_base[b] + off] = make_int2(sh_px[idx], sh_w[idx]);
        }
    }
}

// -------- per-bucket counting sort by dstlocal + fused s1 + sx table + node CSR --------
__global__ __launch_bounds__(256) void k_sort(const int* __restrict__ gbase,
                                              const int* __restrict__ ghist,
                                              int2* __restrict__ rec,
                                              const float* __restrict__ x,
                                              float2* __restrict__ sx,
                                              int* __restrict__ nbase,
                                              int* __restrict__ nend) {
    __shared__ int2 lrec[CAP];          // 44 KB
    __shared__ int hist[NPB];
    __shared__ int excl[NPB];
    __shared__ int cur[NPB];
    __shared__ float loc[NPB];
    const int tid = threadIdx.x;
    if (tid < NPB) { hist[tid] = 0; loc[tid] = 0.f; }
    __syncthreads();
    const int b = blockIdx.x;
    const int beg = gbase[b];
    const int cnt = min(ghist[b], CAP);
    for (int t = tid; t < cnt; t += 256) {
        int2 rc = rec[beg + t];
        lrec[t] = rc;
        int dl = rc.x >> 20;
        atomicAdd(&hist[dl], 1);
        atomicAdd(&loc[dl], __int_as_float(rc.y) * x[rc.x & 0xFFFFF]);  // s1 fused
    }
    __syncthreads();
    if (tid < NPB) excl[tid] = hist[tid];
    __syncthreads();
    #pragma unroll
    for (int off = 1; off < NPB; off <<= 1) {
        int t = (tid < NPB && tid >= off) ? excl[tid - off] : 0;
        __syncthreads();
        if (tid < NPB) excl[tid] += t;
        __syncthreads();
    }
    if (tid < NPB) {
        int e0 = excl[tid] - hist[tid];         // exclusive
        cur[tid] = e0;
        int i = b * NPB + tid;
        if (i < NN) {
            nbase[i] = beg + e0;
            nend[i]  = beg + e0 + hist[tid];
            sx[i] = make_float2(loc[tid], x[i]);   // packed (s1, x)
        }
    }
    __syncthreads();
    for (int t = tid; t < cnt; t += 256) {
        int2 rc = lrec[t];
        int pos = atomicAdd(&cur[rc.x >> 20], 1);
        rec[beg + pos] = rc;                    // scatter within hot 32 KB window
    }
}

__device__ __forceinline__ float rdlane(float v, int k) {
    return __int_as_float(__builtin_amdgcn_readlane(__float_as_int(v), k));
}

// -------- fused layer-2: wave-per-node persistent, pipelined, packed gathers --------
__global__ __launch_bounds__(256, 4) void k_l2_fused(
        const int* __restrict__ nbase, const int* __restrict__ nend,
        const int2* __restrict__ rec,
        const float2* __restrict__ sx,
        const float* __restrict__ W1_rel, const float* __restrict__ W1_root,
        const float* __restrict__ b1,
        const float* __restrict__ W2_rel, const float* __restrict__ b2,
        const float* __restrict__ W2_root,
        const float* __restrict__ W3_rel, const float* __restrict__ W3_root,
        float* __restrict__ p, float* __restrict__ r) {
    const int f = threadIdx.x & 63;

    const float w1r = W1_rel[f], w1t = W1_root[f], b1f = b1[f];
    const float w3r = W3_rel[f], w3t = W3_root[f], b2f = b2[f];

    const int wid = (blockIdx.x * blockDim.x + threadIdx.x) >> 6;
    const int nw  = (gridDim.x * blockDim.x) >> 6;

    for (int i = wid; i < NN; i += nw) {
        const int beg = nbase[i], end = nend[i];
        float a0 = 0.f, a1 = 0.f, a2 = 0.f, a3 = 0.f;
        int e = beg;
        const int nb8 = (end - beg) >> 3;
        if (nb8 > 0) {
            int2 q[8];
            #pragma unroll
            for (int j = 0; j < 8; ++j) q[j] = rec[e + j];
            for (int t = 1; t <= nb8; ++t) {
                // gathers for current batch (one 8B load per edge)
                float2 sv[8];
                #pragma unroll
                for (int j = 0; j < 8; ++j) sv[j] = sx[q[j].x & 0xFFFFF];
                // prefetch next batch records (overlaps with compute below)
                int2 qn[8];
                if (t < nb8) {
                    #pragma unroll
                    for (int j = 0; j < 8; ++j) qn[j] = rec[e + 8 + j];
                }
                #pragma unroll
                for (int j = 0; j < 8; ++j) {
                    const float h = fmaxf(0.f, fmaf(sv[j].x, w1r, fmaf(sv[j].y, w1t, b1f)));
                    const float w = __int_as_float(q[j].y);
                    if ((j & 3) == 0) a0 = fmaf(w, h, a0);
                    else if ((j & 3) == 1) a1 = fmaf(w, h, a1);
                    else if ((j & 3) == 2) a2 = fmaf(w, h, a2);
                    else a3 = fmaf(w, h, a3);
                }
                if (t < nb8) {
                    #pragma unroll
                    for (int j = 0; j < 8; ++j) q[j] = qn[j];
                }
                e += 8;
            }
        }
        for (; e < end; ++e) {
            int2 q0 = rec[e];
            float2 sv = sx[q0.x & 0xFFFFF];
            a0 = fmaf(__int_as_float(q0.y),
                      fmaxf(0.f, fmaf(sv.x, w1r, fmaf(sv.y, w1t, b1f))), a0);
        }
        const float acc = (a0 + a1) + (a2 + a3);
        const float2 svi = sx[i];
        const float hi = fmaxf(0.f, fmaf(svi.x, w1r, fmaf(svi.y, w1t, b1f)));

        float o0 = b2f, o1 = 0.f, o2 = 0.f, o3 = 0.f;
        #pragma unroll
        for (int k = 0; k < HID; k += 4) {
            o0 = fmaf(rdlane(acc, k    ), W2_rel[(k    ) * HID + f], fmaf(rdlane(hi, k    ), W2_root[(k    ) * HID + f], o0));
            o1 = fmaf(rdlane(acc, k + 1), W2_rel[(k + 1) * HID + f], fmaf(rdlane(hi, k + 1), W2_root[(k + 1) * HID + f], o1));
            o2 = fmaf(rdlane(acc, k + 2), W2_rel[(k + 2) * HID + f], fmaf(rdlane(hi, k + 2), W2_root[(k + 2) * HID + f], o2));
            o3 = fmaf(rdlane(acc, k + 3), W2_rel[(k + 3) * HID + f], fmaf(rdlane(hi, k + 3), W2_root[(k + 3) * HID + f], o3));
        }
        const float h2 = fmaxf(0.f, (o0 + o1) + (o2 + o3));

        float pv = h2 * w3r;
        float rv = h2 * w3t;
        #pragma unroll
        for (int off = 32; off; off >>= 1) {
            pv += __shfl_down(pv, off, 64);
            rv += __shfl_down(rv, off, 64);
        }
        if (f == 0) { p[i] = pv; r[i] = rv; }
    }
}

// -------- bucketed output: out = seg_sum(w * p[src]) + r + b3 --------
__global__ __launch_bounds__(256) void k_out(const int* __restrict__ gbase,
                                             const int* __restrict__ ghist,
                                             const int2* __restrict__ rec,
                                             const float* __restrict__ pp,
                                             const float* __restrict__ rr,
                                             const float* __restrict__ b3,
                                             float* __restrict__ out) {
    __shared__ float loc[NPB];
    if (threadIdx.x < NPB) loc[threadIdx.x] = 0.f;
    __syncthreads();
    const int b = blockIdx.x;
    const int beg = gbase[b], cnt = ghist[b];
    for (int t = threadIdx.x; t < cnt; t += 256) {
        int2 rc = rec[beg + t];
        atomicAdd(&loc[rc.x >> 20], __int_as_float(rc.y) * pp[rc.x & 0xFFFFF]);
    }
    __syncthreads();
    int i = b * NPB + threadIdx.x;
    if (threadIdx.x < NPB && i < NN) out[i] = loc[threadIdx.x] + rr[i] + b3[0];
}

extern "C" void kernel_launch(void* const* d_in, const int* in_sizes, int n_in,
                              void* d_out, int out_size, void* d_ws, size_t ws_size,
                              hipStream_t stream) {
    const float* x       = (const float*)d_in[0];
    const int*   ei      = (const int*)  d_in[1];
    const float* ew      = (const float*)d_in[2];
    const float* W1_rel  = (const float*)d_in[3];
    const float* b1      = (const float*)d_in[4];
    const float* W1_root = (const float*)d_in[5];
    const float* W2_rel  = (const float*)d_in[6];
    const float* b2      = (const float*)d_in[7];
    const float* W2_root = (const float*)d_in[8];
    const float* W3_rel  = (const float*)d_in[9];
    const float* b3      = (const float*)d_in[10];
    const float* W3_root = (const float*)d_in[11];

    const int* src = ei;
    const int* dst = ei + NE;

    int2*   rec   = (int2*)d_ws;
    float2* sx    = (float2*)((int*)d_ws + 2 * (size_t)NE);
    float*  p     = (float*)(sx + NN);
    float*  r     = p + NN;
    int*    nbase = (int*)(r + NN);
    int*    nend  = nbase + NN;
    int*    ghist = nend + NN;
    int*    gbase = ghist + NB;
    int*    gcur  = gbase + NB;

    hipMemsetAsync(ghist, 0, NB * sizeof(int), stream);

    k_hist<<<NCH, 256, 0, stream>>>(dst, ghist);
    k_scan<<<1, 1024, 0, stream>>>(ghist, gbase, gcur);
    k_scatter<<<NCH, 256, 0, stream>>>(src, dst, ew, gcur, rec);
    k_sort<<<NB, 256, 0, stream>>>(gbase, ghist, rec, x, sx, nbase, nend);
    k_l2_fused<<<1280, 256, 0, stream>>>(nbase, nend, rec, sx,
                                         W1_rel, W1_root, b1,
                                         W2_rel, b2, W2_root,
                                         W3_rel, W3_root, p, r);
    k_out<<<NB, 256, 0, stream>>>(gbase, ghist, rec, p, r, b3, (float*)d_out);
}

// Round 8
// 509.576 us; speedup vs baseline: 2.7019x; 2.7019x over previous
//
#include <hip/hip_runtime.h>

#define NN 100000
#define NE 3200000
#define HID 64
#define NPB 128                         // nodes per bucket (dstlocal = dst & 127)
#define NB  ((NN + NPB - 1) / NPB)      // 782 buckets
#define CHUNK 4096                      // edges per hist/scatter workgroup
#define NCH ((NE + CHUNK - 1) / CHUNK)  // 782 chunks
#define CAP 5632                        // per-bucket record capacity (mean 4092, sd 64)

// ws layout (4B words), ~28 MB:
//  [0, 2*NE)    rec (int2: .x = src | dstlocal<<20, .y = ew bits) — sorted in place
//  then sx[2NN] (float2: s1,x), p[NN], r[NN], nbase[NN], nend[NN], ghist[NB], gbase[NB], gcur[NB]

// -------- global histogram over dst buckets --------
__global__ __launch_bounds__(256) void k_hist(const int* __restrict__ dst,
                                              int* __restrict__ ghist) {
    __shared__ int sh[NB];
    for (int j = threadIdx.x; j < NB; j += 256) sh[j] = 0;
    __syncthreads();
    const long long b0 = (long long)blockIdx.x * CHUNK;
    #pragma unroll
    for (int k = 0; k < CHUNK / 256; ++k) {
        long long e = b0 + k * 256 + threadIdx.x;
        if (e < NE) atomicAdd(&sh[dst[e] >> 7], 1);
    }
    __syncthreads();
    for (int j = threadIdx.x; j < NB; j += 256) {
        int c = sh[j];
        if (c) atomicAdd(&ghist[j], c);
    }
}

// -------- exclusive scan of NB bucket counts (single WG) --------
__global__ void k_scan(const int* __restrict__ ghist, int* __restrict__ gbase,
                       int* __restrict__ gcur) {
    __shared__ int sh[1024];
    const int tid = threadIdx.x;
    int v = (tid < NB) ? ghist[tid] : 0;
    sh[tid] = v;
    __syncthreads();
    #pragma unroll
    for (int off = 1; off < 1024; off <<= 1) {
        int t = (tid >= off) ? sh[tid - off] : 0;
        __syncthreads();
        sh[tid] += t;
        __syncthreads();
    }
    if (tid < NB) {
        int b = sh[tid] - v;
        gbase[tid] = b;
        gcur[tid] = b;
    }
}

// -------- bucketed scatter: LDS-staged, one reservation atomic per (WG,bucket) --------
__global__ __launch_bounds__(256) void k_scatter(const int* __restrict__ src,
                                                 const int* __restrict__ dst,
                                                 const float* __restrict__ ew,
                                                 int* __restrict__ gcur,
                                                 int2* __restrict__ rec) {
    __shared__ int sh_px[CHUNK];
    __shared__ int sh_w[CHUNK];
    __shared__ unsigned short sh_b[CHUNK];
    __shared__ int sh_cnt[NB];
    __shared__ int sh_base[NB];
    for (int j = threadIdx.x; j < NB; j += 256) sh_cnt[j] = 0;
    __syncthreads();
    const long long b0 = (long long)blockIdx.x * CHUNK;
    #pragma unroll
    for (int k = 0; k < CHUNK / 256; ++k) {
        int idx = k * 256 + threadIdx.x;
        long long e = b0 + idx;
        if (e < NE) {
            int d = dst[e];
            int b = d >> 7;
            sh_px[idx] = src[e] | ((d & 127) << 20);   // src < 2^20
            sh_w[idx] = __float_as_int(ew[e]);
            sh_b[idx] = (unsigned short)b;
            atomicAdd(&sh_cnt[b], 1);
        }
    }
    __syncthreads();
    for (int j = threadIdx.x; j < NB; j += 256) {
        int c = sh_cnt[j];
        sh_base[j] = c ? atomicAdd(&gcur[j], c) : 0;
        sh_cnt[j] = 0;                                  // reuse as running offset
    }
    __syncthreads();
    #pragma unroll
    for (int k = 0; k < CHUNK / 256; ++k) {
        int idx = k * 256 + threadIdx.x;
        long long e = b0 + idx;
        if (e < NE) {
            int b = sh_b[idx];
            int off = atomicAdd(&sh_cnt[b], 1);
            rec[sh_base[b] + off] = make_int2(sh_px[idx], sh_w[idx]);
        }
    }
}

// -------- per-bucket counting sort by dstlocal + fused s1 + sx table + node CSR --------
__global__ __launch_bounds__(256) void k_sort(const int* __restrict__ gbase,
                                              const int* __restrict__ ghist,
                                              int2* __restrict__ rec,
                                              const float* __restrict__ x,
                                              float2* __restrict__ sx,
                                              int* __restrict__ nbase,
                                              int* __restrict__ nend) {
    __shared__ int2 lrec[CAP];          // 44 KB
    __shared__ int hist[NPB];
    __shared__ int excl[NPB];
    __shared__ int cur[NPB];
    __shared__ float loc[NPB];
    const int tid = threadIdx.x;
    if (tid < NPB) { hist[tid] = 0; loc[tid] = 0.f; }
    __syncthreads();
    const int b = blockIdx.x;
    const int beg = gbase[b];
    const int cnt = min(ghist[b], CAP);
    for (int t = tid; t < cnt; t += 256) {
        int2 rc = rec[beg + t];
        lrec[t] = rc;
        int dl = rc.x >> 20;
        atomicAdd(&hist[dl], 1);
        atomicAdd(&loc[dl], __int_as_float(rc.y) * x[rc.x & 0xFFFFF]);  // s1 fused
    }
    __syncthreads();
    if (tid < NPB) excl[tid] = hist[tid];
    __syncthreads();
    #pragma unroll
    for (int off = 1; off < NPB; off <<= 1) {
        int t = (tid < NPB && tid >= off) ? excl[tid - off] : 0;
        __syncthreads();
        if (tid < NPB) excl[tid] += t;
        __syncthreads();
    }
    if (tid < NPB) {
        int e0 = excl[tid] - hist[tid];         // exclusive
        cur[tid] = e0;
        int i = b * NPB + tid;
        if (i < NN) {
            nbase[i] = beg + e0;
            nend[i]  = beg + e0 + hist[tid];
            sx[i] = make_float2(loc[tid], x[i]);   // packed (s1, x)
        }
    }
    __syncthreads();
    for (int t = tid; t < cnt; t += 256) {
        int2 rc = lrec[t];
        int pos = atomicAdd(&cur[rc.x >> 20], 1);
        rec[beg + pos] = rc;                    // scatter within hot 32 KB window
    }
}

__device__ __forceinline__ float rdlane(float v, int k) {
    return __int_as_float(__builtin_amdgcn_readlane(__float_as_int(v), k));
}

// -------- fused layer-2: wave-per-node persistent, R6-proven shape + packed sx --------
// NOTE: (256,2) — NOT (256,4): min-waves=4 caps VGPR at 64 and spills the 8-wide
// batch to scratch (R7: 1.26 GB HBM scratch traffic). R6 shape compiles to 92 VGPR.
__global__ __launch_bounds__(256, 2) void k_l2_fused(
        const int* __restrict__ nbase, const int* __restrict__ nend,
        const int2* __restrict__ rec,
        const float2* __restrict__ sx,
        const float* __restrict__ W1_rel, const float* __restrict__ W1_root,
        const float* __restrict__ b1,
        const float* __restrict__ W2_rel, const float* __restrict__ b2,
        const float* __restrict__ W2_root,
        const float* __restrict__ W3_rel, const float* __restrict__ W3_root,
        float* __restrict__ p, float* __restrict__ r) {
    const int f = threadIdx.x & 63;

    const float w1r = W1_rel[f], w1t = W1_root[f], b1f = b1[f];
    const float w3r = W3_rel[f], w3t = W3_root[f], b2f = b2[f];

    const int wid = (blockIdx.x * blockDim.x + threadIdx.x) >> 6;
    const int nw  = (gridDim.x * blockDim.x) >> 6;

    for (int i = wid; i < NN; i += nw) {
        const int beg = nbase[i], end = nend[i];
        float a0 = 0.f, a1 = 0.f, a2 = 0.f, a3 = 0.f;
        int e = beg;
        for (; e + 8 <= end; e += 8) {
            int2 q0 = rec[e],     q1 = rec[e + 1], q2 = rec[e + 2], q3 = rec[e + 3];
            int2 q4 = rec[e + 4], q5 = rec[e + 5], q6 = rec[e + 6], q7 = rec[e + 7];
            float2 v0 = sx[q0.x & 0xFFFFF];
            float2 v1 = sx[q1.x & 0xFFFFF];
            float2 v2 = sx[q2.x & 0xFFFFF];
            float2 v3 = sx[q3.x & 0xFFFFF];
            float2 v4 = sx[q4.x & 0xFFFFF];
            float2 v5 = sx[q5.x & 0xFFFFF];
            float2 v6 = sx[q6.x & 0xFFFFF];
            float2 v7 = sx[q7.x & 0xFFFFF];
            a0 = fmaf(__int_as_float(q0.y), fmaxf(0.f, fmaf(v0.x, w1r, fmaf(v0.y, w1t, b1f))), a0);
            a1 = fmaf(__int_as_float(q1.y), fmaxf(0.f, fmaf(v1.x, w1r, fmaf(v1.y, w1t, b1f))), a1);
            a2 = fmaf(__int_as_float(q2.y), fmaxf(0.f, fmaf(v2.x, w1r, fmaf(v2.y, w1t, b1f))), a2);
            a3 = fmaf(__int_as_float(q3.y), fmaxf(0.f, fmaf(v3.x, w1r, fmaf(v3.y, w1t, b1f))), a3);
            a0 = fmaf(__int_as_float(q4.y), fmaxf(0.f, fmaf(v4.x, w1r, fmaf(v4.y, w1t, b1f))), a0);
            a1 = fmaf(__int_as_float(q5.y), fmaxf(0.f, fmaf(v5.x, w1r, fmaf(v5.y, w1t, b1f))), a1);
            a2 = fmaf(__int_as_float(q6.y), fmaxf(0.f, fmaf(v6.x, w1r, fmaf(v6.y, w1t, b1f))), a2);
            a3 = fmaf(__int_as_float(q7.y), fmaxf(0.f, fmaf(v7.x, w1r, fmaf(v7.y, w1t, b1f))), a3);
        }
        for (; e < end; ++e) {
            int2 q0 = rec[e];
            float2 sv = sx[q0.x & 0xFFFFF];
            a0 = fmaf(__int_as_float(q0.y),
                      fmaxf(0.f, fmaf(sv.x, w1r, fmaf(sv.y, w1t, b1f))), a0);
        }
        const float acc = (a0 + a1) + (a2 + a3);
        const float2 svi = sx[i];
        const float hi = fmaxf(0.f, fmaf(svi.x, w1r, fmaf(svi.y, w1t, b1f)));

        float o0 = b2f, o1 = 0.f, o2 = 0.f, o3 = 0.f;
        #pragma unroll
        for (int k = 0; k < HID; k += 4) {
            o0 = fmaf(rdlane(acc, k    ), W2_rel[(k    ) * HID + f], fmaf(rdlane(hi, k    ), W2_root[(k    ) * HID + f], o0));
            o1 = fmaf(rdlane(acc, k + 1), W2_rel[(k + 1) * HID + f], fmaf(rdlane(hi, k + 1), W2_root[(k + 1) * HID + f], o1));
            o2 = fmaf(rdlane(acc, k + 2), W2_rel[(k + 2) * HID + f], fmaf(rdlane(hi, k + 2), W2_root[(k + 2) * HID + f], o2));
            o3 = fmaf(rdlane(acc, k + 3), W2_rel[(k + 3) * HID + f], fmaf(rdlane(hi, k + 3), W2_root[(k + 3) * HID + f], o3));
        }
        const float h2 = fmaxf(0.f, (o0 + o1) + (o2 + o3));

        float pv = h2 * w3r;
        float rv = h2 * w3t;
        #pragma unroll
        for (int off = 32; off; off >>= 1) {
            pv += __shfl_down(pv, off, 64);
            rv += __shfl_down(rv, off, 64);
        }
        if (f == 0) { p[i] = pv; r[i] = rv; }
    }
}

// -------- bucketed output: out = seg_sum(w * p[src]) + r + b3 --------
__global__ __launch_bounds__(256) void k_out(const int* __restrict__ gbase,
                                             const int* __restrict__ ghist,
                                             const int2* __restrict__ rec,
                                             const float* __restrict__ pp,
                                             const float* __restrict__ rr,
                                             const float* __restrict__ b3,
                                             float* __restrict__ out) {
    __shared__ float loc[NPB];
    if (threadIdx.x < NPB) loc[threadIdx.x] = 0.f;
    __syncthreads();
    const int b = blockIdx.x;
    const int beg = gbase[b], cnt = ghist[b];
    for (int t = threadIdx.x; t < cnt; t += 256) {
        int2 rc = rec[beg + t];
        atomicAdd(&loc[rc.x >> 20], __int_as_float(rc.y) * pp[rc.x & 0xFFFFF]);
    }
    __syncthreads();
    int i = b * NPB + threadIdx.x;
    if (threadIdx.x < NPB && i < NN) out[i] = loc[threadIdx.x] + rr[i] + b3[0];
}

extern "C" void kernel_launch(void* const* d_in, const int* in_sizes, int n_in,
                              void* d_out, int out_size, void* d_ws, size_t ws_size,
                              hipStream_t stream) {
    const float* x       = (const float*)d_in[0];
    const int*   ei      = (const int*)  d_in[1];
    const float* ew      = (const float*)d_in[2];
    const float* W1_rel  = (const float*)d_in[3];
    const float* b1      = (const float*)d_in[4];
    const float* W1_root = (const float*)d_in[5];
    const float* W2_rel  = (const float*)d_in[6];
    const float* b2      = (const float*)d_in[7];
    const float* W2_root = (const float*)d_in[8];
    const float* W3_rel  = (const float*)d_in[9];
    const float* b3      = (const float*)d_in[10];
    const float* W3_root = (const float*)d_in[11];

    const int* src = ei;
    const int* dst = ei + NE;

    int2*   rec   = (int2*)d_ws;
    float2* sx    = (float2*)((int*)d_ws + 2 * (size_t)NE);
    float*  p     = (float*)(sx + NN);
    float*  r     = p + NN;
    int*    nbase = (int*)(r + NN);
    int*    nend  = nbase + NN;
    int*    ghist = nend + NN;
    int*    gbase = ghist + NB;
    int*    gcur  = gbase + NB;

    hipMemsetAsync(ghist, 0, NB * sizeof(int), stream);

    k_hist<<<NCH, 256, 0, stream>>>(dst, ghist);
    k_scan<<<1, 1024, 0, stream>>>(ghist, gbase, gcur);
    k_scatter<<<NCH, 256, 0, stream>>>(src, dst, ew, gcur, rec);
    k_sort<<<NB, 256, 0, stream>>>(gbase, ghist, rec, x, sx, nbase, nend);
    // grid 2560 (R6's 512 was grid-limited at 2 waves/SIMD; VGPR=92 allows 5)
    k_l2_fused<<<2560, 256, 0, stream>>>(nbase, nend, rec, sx,
                                         W1_rel, W1_root, b1,
                                         W2_rel, b2, W2_root,
                                         W3_rel, W3_root, p, r);
    k_out<<<NB, 256, 0, stream>>>(gbase, ghist, rec, p, r, b3, (float*)d_out);
}